// Round 1
// baseline (2004.752 us; speedup 1.0000x reference)
//
#include <hip/hip_runtime.h>
#include <hip/hip_bf16.h>

// VonMisesNet: B=128, V=128, F=40, H=256, L=32, FL=1024, OUT=1
#define Bsz 128
#define Vn  128
#define Fdim 40
#define Hdim 256
#define Lnum 32
#define FLdim 1024
#define LN_EPS 1e-5f

// ---------------- rowsum: n[b,i] = sum_j G[b,i,j] ----------------
__global__ __launch_bounds__(256) void rowsum_kernel(const float* __restrict__ G,
                                                     float* __restrict__ nrow) {
    int row = blockIdx.x * 4 + (threadIdx.x >> 6);   // global row in [0, B*V)
    int lane = threadIdx.x & 63;
    const float* g = G + (size_t)row * Vn;
    float s = g[lane] + g[lane + 64];
    #pragma unroll
    for (int off = 32; off; off >>= 1) s += __shfl_down(s, off);
    if (lane == 0) nrow[row] = s;
}

// ---------------- feat: v[row,h] = x[row,:]@W_feat[:,h] + b_feat[h] ----------------
__global__ __launch_bounds__(256) void feat_kernel(const float* __restrict__ x,
                                                   const float* __restrict__ Wf,
                                                   const float* __restrict__ bf,
                                                   float* __restrict__ v) {
    __shared__ float xs[Fdim];
    int row = blockIdx.x;
    int h = threadIdx.x;
    if (h < Fdim) xs[h] = x[(size_t)row * Fdim + h];
    __syncthreads();
    float acc = bf[h];
    #pragma unroll 8
    for (int f = 0; f < Fdim; ++f) acc += xs[f] * Wf[f * Hdim + h];
    v[(size_t)row * Hdim + h] = acc;
}

// ---------------- gemm_vw: C[m,n] = A[m,:]@W[:,n] + bias[n]  (M=16384,K=256,N=256) ----------------
__global__ __launch_bounds__(256) void gemm_vw_kernel(const float* __restrict__ A,
                                                      const float* __restrict__ W,
                                                      const float* __restrict__ bias,
                                                      float* __restrict__ C) {
    __shared__ float As[16][64];
    __shared__ float Bs[16][64];
    int m0 = blockIdx.x * 64;
    int n0 = blockIdx.y * 64;
    int tid = threadIdx.x;
    int tx = tid & 15, ty = tid >> 4;
    float acc[4][4] = {};
    int la_m = tid >> 2, la_k = (tid & 3) * 4;
    int lb_k = tid >> 4, lb_n = (tid & 15) * 4;
    for (int k0 = 0; k0 < Hdim; k0 += 16) {
        float4 av = *(const float4*)&A[(size_t)(m0 + la_m) * Hdim + k0 + la_k];
        As[la_k + 0][la_m] = av.x;
        As[la_k + 1][la_m] = av.y;
        As[la_k + 2][la_m] = av.z;
        As[la_k + 3][la_m] = av.w;
        *(float4*)&Bs[lb_k][lb_n] = *(const float4*)&W[(size_t)(k0 + lb_k) * Hdim + n0 + lb_n];
        __syncthreads();
        #pragma unroll
        for (int kk = 0; kk < 16; ++kk) {
            float4 a = *(const float4*)&As[kk][ty * 4];
            float4 b = *(const float4*)&Bs[kk][tx * 4];
            float ar[4] = {a.x, a.y, a.z, a.w};
            float br[4] = {b.x, b.y, b.z, b.w};
            #pragma unroll
            for (int i = 0; i < 4; ++i)
                #pragma unroll
                for (int j = 0; j < 4; ++j)
                    acc[i][j] += ar[i] * br[j];
        }
        __syncthreads();
    }
    #pragma unroll
    for (int i = 0; i < 4; ++i) {
        int m = m0 + ty * 4 + i;
        float4 o;
        int n = n0 + tx * 4;
        o.x = acc[i][0] + bias[n + 0];
        o.y = acc[i][1] + bias[n + 1];
        o.z = acc[i][2] + bias[n + 2];
        o.w = acc[i][3] + bias[n + 3];
        *(float4*)&C[(size_t)m * Hdim + n] = o;
    }
}

// ---------------- msgpass: v[b] += relu((G[b]+diag(n)) @ vp[b] / deg) ----------------
// grid (4 ntiles, 128 batches); output tile 128 rows x 64 cols; thread tile 8x4
__global__ __launch_bounds__(256) void msgpass_kernel(const float* __restrict__ G,
                                                      const float* __restrict__ vp,
                                                      const float* __restrict__ nrow,
                                                      float* __restrict__ v) {
    __shared__ float Gs[16][128];
    __shared__ float Vs[16][64];
    int b = blockIdx.y;
    int n0 = blockIdx.x * 64;
    int tid = threadIdx.x;
    int tx = tid & 15, ty = tid >> 4;
    const float* Gb = G + (size_t)b * Vn * Vn;
    const float* vpb = vp + (size_t)b * Vn * Hdim;
    const float* nb = nrow + b * Vn;
    float acc[8][4] = {};
    int ga_i = tid >> 1, ga_k = (tid & 1) * 8;
    int lb_k = tid >> 4, lb_n = (tid & 15) * 4;
    for (int k0 = 0; k0 < Vn; k0 += 16) {
        #pragma unroll
        for (int u = 0; u < 2; ++u) {
            float4 gv = *(const float4*)&Gb[(size_t)ga_i * Vn + k0 + ga_k + u * 4];
            float vals[4] = {gv.x, gv.y, gv.z, gv.w};
            #pragma unroll
            for (int j = 0; j < 4; ++j) {
                int kk = ga_k + u * 4 + j;
                float val = vals[j];
                if (k0 + kk == ga_i) val += nb[ga_i];   // fold diag(n) into Gp
                Gs[kk][ga_i] = val;
            }
        }
        *(float4*)&Vs[lb_k][lb_n] = *(const float4*)&vpb[(size_t)(k0 + lb_k) * Hdim + n0 + lb_n];
        __syncthreads();
        #pragma unroll
        for (int kk = 0; kk < 16; ++kk) {
            float a[8];
            *(float4*)&a[0] = *(const float4*)&Gs[kk][ty * 8];
            *(float4*)&a[4] = *(const float4*)&Gs[kk][ty * 8 + 4];
            float4 bv = *(const float4*)&Vs[kk][tx * 4];
            float br[4] = {bv.x, bv.y, bv.z, bv.w};
            #pragma unroll
            for (int i = 0; i < 8; ++i)
                #pragma unroll
                for (int j = 0; j < 4; ++j)
                    acc[i][j] += a[i] * br[j];
        }
        __syncthreads();
    }
    #pragma unroll
    for (int i = 0; i < 8; ++i) {
        int row = ty * 8 + i;
        float d = nb[row];
        float deg = d + (d == 0.0f ? 1.0f : 0.0f);
        float inv = 1.0f / deg;
        float* pv = &v[((size_t)b * Vn + row) * Hdim + n0 + tx * 4];
        float4 cur = *(float4*)pv;
        cur.x += fmaxf(acc[i][0] * inv, 0.0f);
        cur.y += fmaxf(acc[i][1] * inv, 0.0f);
        cur.z += fmaxf(acc[i][2] * inv, 0.0f);
        cur.w += fmaxf(acc[i][3] * inv, 0.0f);
        *(float4*)pv = cur;
    }
}

// ---------------- LayerNorm in place over H=256 ----------------
__global__ __launch_bounds__(256) void ln_kernel(float* __restrict__ v,
                                                 const float* __restrict__ g,
                                                 const float* __restrict__ beta) {
    __shared__ float sbuf[4];
    int row = blockIdx.x;
    int t = threadIdx.x;
    float x = v[(size_t)row * Hdim + t];
    float s = x;
    #pragma unroll
    for (int off = 32; off; off >>= 1) s += __shfl_down(s, off);
    int wid = t >> 6, lane = t & 63;
    if (lane == 0) sbuf[wid] = s;
    __syncthreads();
    float mu = (sbuf[0] + sbuf[1] + sbuf[2] + sbuf[3]) * (1.0f / Hdim);
    __syncthreads();
    float d = x - mu;
    float sq = d * d;
    #pragma unroll
    for (int off = 32; off; off >>= 1) sq += __shfl_down(sq, off);
    if (lane == 0) sbuf[wid] = sq;
    __syncthreads();
    float var = (sbuf[0] + sbuf[1] + sbuf[2] + sbuf[3]) * (1.0f / Hdim);
    float h = d * (1.0f / sqrtf(var + LN_EPS)) * g[t] + beta[t];
    v[(size_t)row * Hdim + t] = h;
}

// ---------------- fused final: part[m, nt] = sum_{n in tile} relu(A@Wf + bf)[n] * Wo[n] ----------------
__global__ __launch_bounds__(256) void gemm_fin_kernel(const float* __restrict__ A,
                                                       const float* __restrict__ Wf,
                                                       const float* __restrict__ bf,
                                                       const float* __restrict__ Wo,
                                                       float* __restrict__ part) {
    __shared__ float As[16][64];
    __shared__ float Bs[16][64];
    __shared__ float red[64][17];
    int m0 = blockIdx.x * 64, n0 = blockIdx.y * 64;
    int tid = threadIdx.x, tx = tid & 15, ty = tid >> 4;
    float acc[4][4] = {};
    int la_m = tid >> 2, la_k = (tid & 3) * 4;
    int lb_k = tid >> 4, lb_n = (tid & 15) * 4;
    for (int k0 = 0; k0 < Hdim; k0 += 16) {
        float4 av = *(const float4*)&A[(size_t)(m0 + la_m) * Hdim + k0 + la_k];
        As[la_k + 0][la_m] = av.x;
        As[la_k + 1][la_m] = av.y;
        As[la_k + 2][la_m] = av.z;
        As[la_k + 3][la_m] = av.w;
        *(float4*)&Bs[lb_k][lb_n] = *(const float4*)&Wf[(size_t)(k0 + lb_k) * FLdim + n0 + lb_n];
        __syncthreads();
        #pragma unroll
        for (int kk = 0; kk < 16; ++kk) {
            float4 a = *(const float4*)&As[kk][ty * 4];
            float4 b = *(const float4*)&Bs[kk][tx * 4];
            float ar[4] = {a.x, a.y, a.z, a.w};
            float br[4] = {b.x, b.y, b.z, b.w};
            #pragma unroll
            for (int i = 0; i < 4; ++i)
                #pragma unroll
                for (int j = 0; j < 4; ++j)
                    acc[i][j] += ar[i] * br[j];
        }
        __syncthreads();
    }
    float rsum[4] = {};
    #pragma unroll
    for (int j = 0; j < 4; ++j) {
        int n = n0 + tx * 4 + j;
        float bfv = bf[n], wov = Wo[n];
        #pragma unroll
        for (int i = 0; i < 4; ++i) {
            float h = fmaxf(acc[i][j] + bfv, 0.0f);
            rsum[i] += h * wov;
        }
    }
    #pragma unroll
    for (int i = 0; i < 4; ++i) red[ty * 4 + i][tx] = rsum[i];
    __syncthreads();
    if (tid < 64) {
        float s = 0.0f;
        #pragma unroll
        for (int t = 0; t < 16; ++t) s += red[tid][t];
        part[(size_t)(m0 + tid) * 16 + blockIdx.y] = s;
    }
}

// ---------------- final reduce: out[m] = b_out + sum_t part[m,t] ----------------
__global__ __launch_bounds__(256) void final_kernel(const float* __restrict__ part,
                                                    const float* __restrict__ bo,
                                                    float* __restrict__ out) {
    int i = blockIdx.x * 256 + threadIdx.x;
    float s = bo[0];
    #pragma unroll
    for (int t = 0; t < 16; ++t) s += part[(size_t)i * 16 + t];
    out[i] = s;
}

extern "C" void kernel_launch(void* const* d_in, const int* in_sizes, int n_in,
                              void* d_out, int out_size, void* d_ws, size_t ws_size,
                              hipStream_t stream) {
    const float* x        = (const float*)d_in[0];
    const float* G        = (const float*)d_in[1];
    const float* W_feat   = (const float*)d_in[2];
    const float* b_feat   = (const float*)d_in[3];
    const float* W_layers = (const float*)d_in[4];
    const float* b_layers = (const float*)d_in[5];
    const float* ln_g     = (const float*)d_in[6];
    const float* ln_b     = (const float*)d_in[7];
    const float* W_fin    = (const float*)d_in[8];
    const float* b_fin    = (const float*)d_in[9];
    const float* W_out    = (const float*)d_in[10];
    const float* b_out    = (const float*)d_in[11];
    float* out = (float*)d_out;

    const int M = Bsz * Vn;            // 16384
    float* v    = (float*)d_ws;        // M*H
    float* vp   = v + (size_t)M * Hdim;
    float* nrow = vp + (size_t)M * Hdim;   // M
    float* part = nrow + M;                // M*16

    rowsum_kernel<<<M / 4, 256, 0, stream>>>(G, nrow);
    feat_kernel<<<M, 256, 0, stream>>>(x, W_feat, b_feat, v);

    for (int l = 0; l < Lnum; ++l) {
        gemm_vw_kernel<<<dim3(M / 64, Hdim / 64), 256, 0, stream>>>(
            v, W_layers + (size_t)l * Hdim * Hdim, b_layers + (size_t)l * Hdim, vp);
        msgpass_kernel<<<dim3(Hdim / 64, Bsz), 256, 0, stream>>>(G, vp, nrow, v);
    }

    ln_kernel<<<M, 256, 0, stream>>>(v, ln_g, ln_b);
    gemm_fin_kernel<<<dim3(M / 64, FLdim / 64), 256, 0, stream>>>(v, W_fin, b_fin, W_out, part);
    final_kernel<<<M / 256, 256, 0, stream>>>(part, b_out, out);
}

// Round 3
// 1792.916 us; speedup vs baseline: 1.1182x; 1.1182x over previous
//
#include <hip/hip_runtime.h>

// VonMisesNet: B=128, V=128, F=40, H=256, L=32, FL=1024, OUT=1
#define Bsz 128
#define Vn  128
#define Fdim 40
#define Hdim 256
#define Lnum 32
#define FLdim 1024
#define LN_EPS 1e-5f

typedef unsigned short u16;
typedef __attribute__((ext_vector_type(8))) short short8;
typedef __attribute__((ext_vector_type(4))) float f32x4;

__device__ __forceinline__ u16 f2bf(float f) {
    unsigned u = __float_as_uint(f);
    u += 0x7fff + ((u >> 16) & 1);          // round-to-nearest-even
    return (u16)(u >> 16);
}
__device__ __forceinline__ float bf2f(u16 s) {
    return __uint_as_float((unsigned)s << 16);
}

// stage a [ISSUES*32 rows x 64 k] bf16 tile (row = 128 bytes) into linear LDS
// via registers + ds_write (simple, hazard-free; no async DMA)
template <int ISSUES>
__device__ __forceinline__ void stage_reg(const char* __restrict__ g, size_t rs,
                                          char* lds, int tid) {
    uint4 tmp[ISSUES];
    #pragma unroll
    for (int u = 0; u < ISSUES; ++u) {
        int off = (u * 256 + tid) * 16;
        tmp[u] = *(const uint4*)(g + (size_t)(off >> 7) * rs + (off & 127));
    }
    #pragma unroll
    for (int u = 0; u < ISSUES; ++u) {
        int off = (u * 256 + tid) * 16;
        *(uint4*)(lds + off) = tmp[u];
    }
}

// one BK=64 k-step: A-tile 128x64, B-tile 64x64, wave (wr,wc) does 64x32 out
__device__ __forceinline__ void mma_step(const char* LA, const char* LB,
                                         f32x4 (&acc)[4][2], int wr, int wc, int l) {
    const int lr = l & 15;
    const int lk = (l >> 4) * 16;
    #pragma unroll
    for (int kk = 0; kk < 2; ++kk) {
        short8 a[4], b2[2];
        #pragma unroll
        for (int mi = 0; mi < 4; ++mi)
            a[mi] = *(const short8*)(LA + (wr * 64 + mi * 16 + lr) * 128 + kk * 64 + lk);
        #pragma unroll
        for (int ni = 0; ni < 2; ++ni)
            b2[ni] = *(const short8*)(LB + (wc * 32 + ni * 16 + lr) * 128 + kk * 64 + lk);
        #pragma unroll
        for (int mi = 0; mi < 4; ++mi)
            #pragma unroll
            for (int ni = 0; ni < 2; ++ni)
                acc[mi][ni] = __builtin_amdgcn_mfma_f32_16x16x32_bf16(a[mi], b2[ni],
                                                                     acc[mi][ni], 0, 0, 0);
    }
}

// ---------------- rowsum: n[m] = sum_j G[m,j]; invdeg = 1/(n + (n==0)) ----------------
__global__ __launch_bounds__(256) void rowsum_kernel(const float* __restrict__ G,
                                                     float* __restrict__ nrow,
                                                     float* __restrict__ invdeg) {
    int row = blockIdx.x * 4 + (threadIdx.x >> 6);
    int lane = threadIdx.x & 63;
    const float* g = G + (size_t)row * Vn;
    float s = g[lane] + g[lane + 64];
    #pragma unroll
    for (int off = 32; off; off >>= 1) s += __shfl_down(s, off);
    if (lane == 0) {
        nrow[row] = s;
        invdeg[row] = 1.0f / (s + (s == 0.0f ? 1.0f : 0.0f));
    }
}

// ---------------- Gbf[b][i][j] = bf16(G + diag(n)) (exact: 0/1/int) ----------------
__global__ __launch_bounds__(256) void gbf_kernel(const float* __restrict__ G,
                                                  const float* __restrict__ nrow,
                                                  u16* __restrict__ gbf) {
    int gid = blockIdx.x * 256 + threadIdx.x;      // handles 8 j's
    int j8 = gid & 15;
    int m  = gid >> 4;                             // b*128 + i
    int i  = m & 127;
    const float* src = G + (size_t)m * Vn + j8 * 8;
    float4 g0 = *(const float4*)src;
    float4 g1 = *(const float4*)(src + 4);
    float nb = nrow[m];
    float ge[8] = {g0.x, g0.y, g0.z, g0.w, g1.x, g1.y, g1.z, g1.w};
    u16 us[8];
    #pragma unroll
    for (int e = 0; e < 8; ++e) {
        float val = ge[e] + ((j8 * 8 + e) == i ? nb : 0.0f);
        us[e] = f2bf(val);
    }
    uint4 pack;
    pack.x = (unsigned)us[0] | ((unsigned)us[1] << 16);
    pack.y = (unsigned)us[2] | ((unsigned)us[3] << 16);
    pack.z = (unsigned)us[4] | ((unsigned)us[5] << 16);
    pack.w = (unsigned)us[6] | ((unsigned)us[7] << 16);
    *(uint4*)(gbf + (size_t)m * Vn + j8 * 8) = pack;
}

// ------------- transpose+split: src[K][N] f32 -> hi/lo[N][K] bf16 (per blockIdx.z mat) -------------
__global__ __launch_bounds__(256) void tsplit_kernel(const float* __restrict__ src,
                                                     u16* __restrict__ hi, u16* __restrict__ lo,
                                                     int N, int K) {
    __shared__ float tl[64][65];
    size_t mat = (size_t)blockIdx.z * K * N;
    int k0 = blockIdx.x * 64, n0 = blockIdx.y * 64;
    int t = threadIdx.x, c = t & 63, r4 = t >> 6;
    #pragma unroll
    for (int i = 0; i < 16; ++i) {
        int r = i * 4 + r4;
        tl[r][c] = src[mat + (size_t)(k0 + r) * N + n0 + c];
    }
    __syncthreads();
    #pragma unroll
    for (int i = 0; i < 16; ++i) {
        int nr = i * 4 + r4;
        float val = tl[c][nr];
        u16 h = f2bf(val);
        size_t idx = mat + (size_t)(n0 + nr) * K + k0 + c;
        hi[idx] = h;
        lo[idx] = f2bf(val - bf2f(h));
    }
}

// ---------------- feat: v = x@W_feat + b_feat; also write split ----------------
__global__ __launch_bounds__(256) void feat_kernel(const float* __restrict__ x,
                                                   const float* __restrict__ Wf,
                                                   const float* __restrict__ bf,
                                                   float* __restrict__ v,
                                                   u16* __restrict__ vhi,
                                                   u16* __restrict__ vlo) {
    __shared__ float xs[Fdim];
    int row = blockIdx.x;
    int h = threadIdx.x;
    if (h < Fdim) xs[h] = x[(size_t)row * Fdim + h];
    __syncthreads();
    float acc = bf[h];
    #pragma unroll 8
    for (int f = 0; f < Fdim; ++f) acc += xs[f] * Wf[f * Hdim + h];
    size_t idx = (size_t)row * Hdim + h;
    v[idx] = acc;
    u16 hb = f2bf(acc);
    vhi[idx] = hb;
    vlo[idx] = f2bf(acc - bf2f(hb));
}

// ---------------- gemm_vw: vpT[b][n][i] = split(v@W + b), MFMA split-bf16 ----------------
// grid (128 m-blocks, 4 n-blocks); K' = 768 (hi*hi + lo*hi + hi*lo)
__global__ __launch_bounds__(256) void gemm_vw_mfma(const u16* __restrict__ vhi,
                                                    const u16* __restrict__ vlo,
                                                    const u16* __restrict__ wthi,
                                                    const u16* __restrict__ wtlo,
                                                    const float* __restrict__ bias,
                                                    u16* __restrict__ outhi,
                                                    u16* __restrict__ outlo) {
    __shared__ char smem[24576];
    char* As = smem;
    char* Bs = smem + 16384;
    int tid = threadIdx.x, l = tid & 63, w = tid >> 6, wr = w >> 1, wc = w & 1;
    int m0 = blockIdx.x * 128, n0 = blockIdx.y * 64;
    const char* segA[3] = {(const char*)vhi, (const char*)vlo, (const char*)vhi};
    const char* segB[3] = {(const char*)wthi, (const char*)wthi, (const char*)wtlo};
    f32x4 z = {0.f, 0.f, 0.f, 0.f};
    f32x4 acc[4][2];
    #pragma unroll
    for (int mi = 0; mi < 4; ++mi) { acc[mi][0] = z; acc[mi][1] = z; }

    for (int q = 0; q < 12; ++q) {
        const char* A = segA[q >> 2] + (size_t)m0 * 512 + (q & 3) * 128;
        const char* B = segB[q >> 2] + (size_t)n0 * 512 + (q & 3) * 128;
        stage_reg<4>(A, 512, As, tid);
        stage_reg<2>(B, 512, Bs, tid);
        __syncthreads();
        mma_step(As, Bs, acc, wr, wc, l);
        __syncthreads();
    }
    // epilogue: +bias, split, transposed store vpT[b][n][i] (4 contiguous i per lane)
    int b = blockIdx.x;
    #pragma unroll
    for (int ni = 0; ni < 2; ++ni) {
        int n = n0 + wc * 32 + ni * 16 + (l & 15);
        float bv = bias[n];
        size_t obase = (size_t)b * 32768 + (size_t)n * 128;
        #pragma unroll
        for (int mi = 0; mi < 4; ++mi) {
            int i0 = wr * 64 + mi * 16 + (l >> 4) * 4;
            ushort4 hv, lv;
            float v0 = acc[mi][ni][0] + bv;
            float v1 = acc[mi][ni][1] + bv;
            float v2 = acc[mi][ni][2] + bv;
            float v3 = acc[mi][ni][3] + bv;
            hv.x = f2bf(v0); lv.x = f2bf(v0 - bf2f(hv.x));
            hv.y = f2bf(v1); lv.y = f2bf(v1 - bf2f(hv.y));
            hv.z = f2bf(v2); lv.z = f2bf(v2 - bf2f(hv.z));
            hv.w = f2bf(v3); lv.w = f2bf(v3 - bf2f(hv.w));
            *(ushort4*)(outhi + obase + i0) = hv;
            *(ushort4*)(outlo + obase + i0) = lv;
        }
    }
}

// ---------------- msgpass: v += relu((Gp@vp)/deg); Gbf exact ----------------
// computes mT[d][i] = sum_j vpT[d][j] * Gbf[i][j]; grid (2 dblk, 2 iblk, 128 b); K' = 256
__global__ __launch_bounds__(256) void msgpass_mfma(const u16* __restrict__ vpThi,
                                                    const u16* __restrict__ vpTlo,
                                                    const u16* __restrict__ gbf,
                                                    const float* __restrict__ invdeg,
                                                    float* __restrict__ v,
                                                    u16* __restrict__ vhi,
                                                    u16* __restrict__ vlo) {
    __shared__ char smem[24576];
    char* As = smem;
    char* Bs = smem + 16384;
    int tid = threadIdx.x, l = tid & 63, w = tid >> 6, wr = w >> 1, wc = w & 1;
    int d0 = blockIdx.x * 128, i0 = blockIdx.y * 64, b = blockIdx.z;
    const char* Ab[2] = {(const char*)vpThi + (size_t)b * 65536,
                         (const char*)vpTlo + (size_t)b * 65536};
    const char* Bb = (const char*)gbf + (size_t)b * 32768;
    f32x4 z = {0.f, 0.f, 0.f, 0.f};
    f32x4 acc[4][2];
    #pragma unroll
    for (int mi = 0; mi < 4; ++mi) { acc[mi][0] = z; acc[mi][1] = z; }

    for (int q = 0; q < 4; ++q) {
        const char* A = Ab[q >> 1] + (size_t)d0 * 256 + (q & 1) * 128;
        const char* B = Bb + (size_t)i0 * 256 + (q & 1) * 128;
        stage_reg<4>(A, 256, As, tid);
        stage_reg<2>(B, 256, Bs, tid);
        __syncthreads();
        mma_step(As, Bs, acc, wr, wc, l);
        __syncthreads();
    }
    // epilogue: C row = d, col = i; per lane 4 contiguous d at fixed vertex i
    #pragma unroll
    for (int ni = 0; ni < 2; ++ni) {
        int i = i0 + wc * 32 + ni * 16 + (l & 15);
        int m = b * 128 + i;
        float idg = invdeg[m];
        #pragma unroll
        for (int mi = 0; mi < 4; ++mi) {
            int d = d0 + wr * 64 + mi * 16 + (l >> 4) * 4;
            float* pv = v + (size_t)m * 256 + d;
            float4 c4 = *(float4*)pv;
            float n0v = c4.x + fmaxf(acc[mi][ni][0] * idg, 0.0f);
            float n1v = c4.y + fmaxf(acc[mi][ni][1] * idg, 0.0f);
            float n2v = c4.z + fmaxf(acc[mi][ni][2] * idg, 0.0f);
            float n3v = c4.w + fmaxf(acc[mi][ni][3] * idg, 0.0f);
            *(float4*)pv = make_float4(n0v, n1v, n2v, n3v);
            ushort4 hv, lv;
            hv.x = f2bf(n0v); lv.x = f2bf(n0v - bf2f(hv.x));
            hv.y = f2bf(n1v); lv.y = f2bf(n1v - bf2f(hv.y));
            hv.z = f2bf(n2v); lv.z = f2bf(n2v - bf2f(hv.z));
            hv.w = f2bf(n3v); lv.w = f2bf(n3v - bf2f(hv.w));
            *(ushort4*)(vhi + (size_t)m * 256 + d) = hv;
            *(ushort4*)(vlo + (size_t)m * 256 + d) = lv;
        }
    }
}

// ---------------- LayerNorm: read v fp32, write split h ----------------
__global__ __launch_bounds__(256) void ln_kernel(const float* __restrict__ v,
                                                 const float* __restrict__ g,
                                                 const float* __restrict__ beta,
                                                 u16* __restrict__ hhi,
                                                 u16* __restrict__ hlo) {
    __shared__ float sbuf[4];
    int row = blockIdx.x;
    int t = threadIdx.x;
    float x = v[(size_t)row * Hdim + t];
    float s = x;
    #pragma unroll
    for (int off = 32; off; off >>= 1) s += __shfl_down(s, off);
    int wid = t >> 6, lane = t & 63;
    if (lane == 0) sbuf[wid] = s;
    __syncthreads();
    float mu = (sbuf[0] + sbuf[1] + sbuf[2] + sbuf[3]) * (1.0f / Hdim);
    __syncthreads();
    float d = x - mu;
    float sq = d * d;
    #pragma unroll
    for (int off = 32; off; off >>= 1) sq += __shfl_down(sq, off);
    if (lane == 0) sbuf[wid] = sq;
    __syncthreads();
    float var = (sbuf[0] + sbuf[1] + sbuf[2] + sbuf[3]) * (1.0f / Hdim);
    float h = d * (1.0f / sqrtf(var + LN_EPS)) * g[t] + beta[t];
    size_t idx = (size_t)row * Hdim + t;
    u16 hb = f2bf(h);
    hhi[idx] = hb;
    hlo[idx] = f2bf(h - bf2f(hb));
}

// ---------------- fused final GEMM (MFMA split): part[m][nb] = sum_n relu(h@Wf+bf)*Wo ----------------
// grid (128 m-blocks, 16 n-blocks); K' = 768
__global__ __launch_bounds__(256) void gemm_fin_mfma(const u16* __restrict__ hhi,
                                                     const u16* __restrict__ hlo,
                                                     const u16* __restrict__ wfhi,
                                                     const u16* __restrict__ wflo,
                                                     const float* __restrict__ bfin,
                                                     const float* __restrict__ wout,
                                                     float* __restrict__ part) {
    __shared__ char smem[24576];
    char* As = smem;
    char* Bs = smem + 16384;
    int tid = threadIdx.x, l = tid & 63, w = tid >> 6, wr = w >> 1, wc = w & 1;
    int m0 = blockIdx.x * 128, n0 = blockIdx.y * 64;
    const char* segA[3] = {(const char*)hhi, (const char*)hlo, (const char*)hhi};
    const char* segB[3] = {(const char*)wfhi, (const char*)wfhi, (const char*)wflo};
    f32x4 z = {0.f, 0.f, 0.f, 0.f};
    f32x4 acc[4][2];
    #pragma unroll
    for (int mi = 0; mi < 4; ++mi) { acc[mi][0] = z; acc[mi][1] = z; }

    for (int q = 0; q < 12; ++q) {
        const char* A = segA[q >> 2] + (size_t)m0 * 512 + (q & 3) * 128;
        const char* B = segB[q >> 2] + (size_t)n0 * 512 + (q & 3) * 128;
        stage_reg<4>(A, 512, As, tid);
        stage_reg<2>(B, 512, Bs, tid);
        __syncthreads();
        mma_step(As, Bs, acc, wr, wc, l);
        __syncthreads();
    }
    // epilogue: relu(+bias)*Wo, reduce over this block's 64 n-cols
    float rs[4][4];
    #pragma unroll
    for (int mi = 0; mi < 4; ++mi)
        #pragma unroll
        for (int r = 0; r < 4; ++r) rs[mi][r] = 0.0f;
    #pragma unroll
    for (int ni = 0; ni < 2; ++ni) {
        int n = n0 + wc * 32 + ni * 16 + (l & 15);
        float bv = bfin[n], wo = wout[n];
        #pragma unroll
        for (int mi = 0; mi < 4; ++mi)
            #pragma unroll
            for (int r = 0; r < 4; ++r)
                rs[mi][r] += fmaxf(acc[mi][ni][r] + bv, 0.0f) * wo;
    }
    float* red = (float*)smem;          // [128][33] floats = 16.9 KB; loop ended with barrier
    #pragma unroll
    for (int mi = 0; mi < 4; ++mi)
        #pragma unroll
        for (int r = 0; r < 4; ++r) {
            int row = wr * 64 + mi * 16 + (l >> 4) * 4 + r;
            red[row * 33 + wc * 16 + (l & 15)] = rs[mi][r];
        }
    __syncthreads();
    if (tid < 128) {
        float s = 0.0f;
        #pragma unroll
        for (int c = 0; c < 32; ++c) s += red[tid * 33 + c];
        part[(size_t)(m0 + tid) * 16 + blockIdx.y] = s;
    }
}

// ---------------- final reduce ----------------
__global__ __launch_bounds__(256) void final_kernel(const float* __restrict__ part,
                                                    const float* __restrict__ bo,
                                                    float* __restrict__ out) {
    int i = blockIdx.x * 256 + threadIdx.x;
    float s = bo[0];
    #pragma unroll
    for (int t = 0; t < 16; ++t) s += part[(size_t)i * 16 + t];
    out[i] = s;
}

extern "C" void kernel_launch(void* const* d_in, const int* in_sizes, int n_in,
                              void* d_out, int out_size, void* d_ws, size_t ws_size,
                              hipStream_t stream) {
    const float* x        = (const float*)d_in[0];
    const float* G        = (const float*)d_in[1];
    const float* W_feat   = (const float*)d_in[2];
    const float* b_feat   = (const float*)d_in[3];
    const float* W_layers = (const float*)d_in[4];
    const float* b_layers = (const float*)d_in[5];
    const float* ln_g     = (const float*)d_in[6];
    const float* ln_b     = (const float*)d_in[7];
    const float* W_fin    = (const float*)d_in[8];
    const float* b_fin    = (const float*)d_in[9];
    const float* W_out    = (const float*)d_in[10];
    const float* b_out    = (const float*)d_in[11];
    float* out = (float*)d_out;

    const int M = Bsz * Vn;                          // 16384
    char* ws = (char*)d_ws;
    float* v      = (float*)ws;                      ws += (size_t)M * Hdim * 4;     // 16 MB
    u16*   vhi    = (u16*)ws;                        ws += (size_t)M * Hdim * 2;     // 8 MB
    u16*   vlo    = (u16*)ws;                        ws += (size_t)M * Hdim * 2;     // 8 MB
    u16*   vpThi  = (u16*)ws;                        ws += (size_t)M * Hdim * 2;     // 8 MB
    u16*   vpTlo  = (u16*)ws;                        ws += (size_t)M * Hdim * 2;     // 8 MB
    u16*   gbf    = (u16*)ws;                        ws += (size_t)Bsz * Vn * Vn * 2;   // 4 MB
    u16*   wthi   = (u16*)ws;                        ws += (size_t)Lnum * Hdim * Hdim * 2; // 4 MB
    u16*   wtlo   = (u16*)ws;                        ws += (size_t)Lnum * Hdim * Hdim * 2; // 4 MB
    u16*   wfhi   = (u16*)ws;                        ws += (size_t)FLdim * Hdim * 2;  // 0.5 MB
    u16*   wflo   = (u16*)ws;                        ws += (size_t)FLdim * Hdim * 2;  // 0.5 MB
    float* nrow   = (float*)ws;                      ws += (size_t)M * 4;
    float* invdeg = (float*)ws;                      ws += (size_t)M * 4;
    float* part   = (float*)ws;                      ws += (size_t)M * 16 * 4;        // 1 MB

    rowsum_kernel<<<M / 4, 256, 0, stream>>>(G, nrow, invdeg);
    gbf_kernel<<<(Bsz * Vn * 16) / 256, 256, 0, stream>>>(G, nrow, gbf);
    tsplit_kernel<<<dim3(4, 4, Lnum), 256, 0, stream>>>(W_layers, wthi, wtlo, Hdim, Hdim);
    tsplit_kernel<<<dim3(4, 16, 1), 256, 0, stream>>>(W_fin, wfhi, wflo, FLdim, Hdim);
    feat_kernel<<<M, 256, 0, stream>>>(x, W_feat, b_feat, v, vhi, vlo);

    for (int l = 0; l < Lnum; ++l) {
        gemm_vw_mfma<<<dim3(M / 128, Hdim / 64), 256, 0, stream>>>(
            vhi, vlo, wthi + (size_t)l * Hdim * Hdim, wtlo + (size_t)l * Hdim * Hdim,
            b_layers + (size_t)l * Hdim, vpThi, vpTlo);
        msgpass_mfma<<<dim3(2, 2, Bsz), 256, 0, stream>>>(
            vpThi, vpTlo, gbf, invdeg, v, vhi, vlo);
    }

    ln_kernel<<<M, 256, 0, stream>>>(v, ln_g, ln_b, vhi, vlo);
    gemm_fin_mfma<<<dim3(M / 128, FLdim / 64), 256, 0, stream>>>(
        vhi, vlo, wfhi, wflo, b_fin, W_out, part);
    final_kernel<<<M / 256, 256, 0, stream>>>(part, b_out, out);
}

// Round 4
// 1655.016 us; speedup vs baseline: 1.2113x; 1.0833x over previous
//
#include <hip/hip_runtime.h>

// VonMisesNet: B=128, V=128, F=40, H=256, L=32, FL=1024, OUT=1
#define Bsz 128
#define Vn  128
#define Fdim 40
#define Hdim 256
#define Lnum 32
#define FLdim 1024
#define LN_EPS 1e-5f

typedef unsigned short u16;
typedef __attribute__((ext_vector_type(8))) short short8;
typedef __attribute__((ext_vector_type(4))) float f32x4;

__device__ __forceinline__ u16 f2bf(float f) {
    unsigned u = __float_as_uint(f);
    u += 0x7fff + ((u >> 16) & 1);          // round-to-nearest-even
    return (u16)(u >> 16);
}
__device__ __forceinline__ float bf2f(u16 s) {
    return __uint_as_float((unsigned)s << 16);
}

// ---------------- rowsum: n[m] = sum_j G[m,j]; invdeg = 1/(n + (n==0)) ----------------
__global__ __launch_bounds__(256) void rowsum_kernel(const float* __restrict__ G,
                                                     float* __restrict__ nrow,
                                                     float* __restrict__ invdeg) {
    int row = blockIdx.x * 4 + (threadIdx.x >> 6);
    int lane = threadIdx.x & 63;
    const float* g = G + (size_t)row * Vn;
    float s = g[lane] + g[lane + 64];
    #pragma unroll
    for (int off = 32; off; off >>= 1) s += __shfl_down(s, off);
    if (lane == 0) {
        nrow[row] = s;
        invdeg[row] = 1.0f / (s + (s == 0.0f ? 1.0f : 0.0f));
    }
}

// ---------------- Gbf[b][i][j] = bf16(G + diag(n)) (exact: 0/1/int) ----------------
__global__ __launch_bounds__(256) void gbf_kernel(const float* __restrict__ G,
                                                  const float* __restrict__ nrow,
                                                  u16* __restrict__ gbf) {
    int gid = blockIdx.x * 256 + threadIdx.x;      // handles 8 j's
    int j8 = gid & 15;
    int m  = gid >> 4;                             // b*128 + i
    int i  = m & 127;
    const float* src = G + (size_t)m * Vn + j8 * 8;
    float4 g0 = *(const float4*)src;
    float4 g1 = *(const float4*)(src + 4);
    float nb = nrow[m];
    float ge[8] = {g0.x, g0.y, g0.z, g0.w, g1.x, g1.y, g1.z, g1.w};
    u16 us[8];
    #pragma unroll
    for (int e = 0; e < 8; ++e) {
        float val = ge[e] + ((j8 * 8 + e) == i ? nb : 0.0f);
        us[e] = f2bf(val);
    }
    uint4 pack;
    pack.x = (unsigned)us[0] | ((unsigned)us[1] << 16);
    pack.y = (unsigned)us[2] | ((unsigned)us[3] << 16);
    pack.z = (unsigned)us[4] | ((unsigned)us[5] << 16);
    pack.w = (unsigned)us[6] | ((unsigned)us[7] << 16);
    *(uint4*)(gbf + (size_t)m * Vn + j8 * 8) = pack;
}

// ------------- transpose+split: src[K][N] f32 -> hi/lo[N][K] bf16 (per blockIdx.z mat) -------------
__global__ __launch_bounds__(256) void tsplit_kernel(const float* __restrict__ src,
                                                     u16* __restrict__ hi, u16* __restrict__ lo,
                                                     int N, int K) {
    __shared__ float tl[64][65];
    size_t mat = (size_t)blockIdx.z * K * N;
    int k0 = blockIdx.x * 64, n0 = blockIdx.y * 64;
    int t = threadIdx.x, c = t & 63, r4 = t >> 6;
    #pragma unroll
    for (int i = 0; i < 16; ++i) {
        int r = i * 4 + r4;
        tl[r][c] = src[mat + (size_t)(k0 + r) * N + n0 + c];
    }
    __syncthreads();
    #pragma unroll
    for (int i = 0; i < 16; ++i) {
        int nr = i * 4 + r4;
        float val = tl[c][nr];
        u16 h = f2bf(val);
        size_t idx = mat + (size_t)(n0 + nr) * K + k0 + c;
        hi[idx] = h;
        lo[idx] = f2bf(val - bf2f(h));
    }
}

// ---------------- feat: v = x@W_feat + b_feat; also write split ----------------
__global__ __launch_bounds__(256) void feat_kernel(const float* __restrict__ x,
                                                   const float* __restrict__ Wf,
                                                   const float* __restrict__ bf,
                                                   float* __restrict__ v,
                                                   u16* __restrict__ vhi,
                                                   u16* __restrict__ vlo) {
    __shared__ float xs[Fdim];
    int row = blockIdx.x;
    int h = threadIdx.x;
    if (h < Fdim) xs[h] = x[(size_t)row * Fdim + h];
    __syncthreads();
    float acc = bf[h];
    #pragma unroll 8
    for (int f = 0; f < Fdim; ++f) acc += xs[f] * Wf[f * Hdim + h];
    size_t idx = (size_t)row * Hdim + h;
    v[idx] = acc;
    u16 hb = f2bf(acc);
    vhi[idx] = hb;
    vlo[idx] = f2bf(acc - bf2f(hb));
}

// ================= fused layer: vp = v@W+b (LDS), m = Gp@vp, v += relu(m/deg) =================
// grid (2 d-halves, 128 batches), 256 threads (4 waves, 2x2 wave grid of 64x64 tiles)
// dynamic LDS 128KB: Gs[128i][128j] | VPH[128d][128j] | VPL | As[128][64k] | Bs[128][64k]
__global__ __launch_bounds__(256) void layer_fused(const u16* __restrict__ vhi_in,
                                                   const u16* __restrict__ vlo_in,
                                                   const u16* __restrict__ wthi,
                                                   const u16* __restrict__ wtlo,
                                                   const float* __restrict__ bias,
                                                   const u16* __restrict__ gbf,
                                                   const float* __restrict__ invdeg,
                                                   float* __restrict__ v,
                                                   u16* __restrict__ vhi_out,
                                                   u16* __restrict__ vlo_out) {
    extern __shared__ char smem[];
    char* Gs  = smem;                // 32768
    char* VPH = smem + 32768;        // 32768
    char* VPL = smem + 65536;        // 32768
    char* As  = smem + 98304;        // 16384
    char* Bs  = smem + 114688;       // 16384

    int tid = threadIdx.x, l = tid & 63, w = tid >> 6, wr = w >> 1, wc = w & 1;
    int dh = blockIdx.x;             // d-half (0/1)
    int b  = blockIdx.y;
    const int lr = l & 15;
    const int lkb = (l >> 4) * 16;   // byte offset of this lane's 8-elem k-group

    // ---- stage Gs (whole 128x128 bf16 adjacency block, linear copy) ----
    const char* gb = (const char*)gbf + (size_t)b * 32768;
    #pragma unroll
    for (int u = 0; u < 8; ++u) {
        int off = (u * 256 + tid) * 16;
        *(uint4*)(Gs + off) = *(const uint4*)(gb + off);
    }

    // ---- GEMM1: vp[j][d-cols] = v[b] @ W[:, d-cols], split-bf16 K'=768 ----
    const char* Ain[3] = {(const char*)vhi_in, (const char*)vlo_in, (const char*)vhi_in};
    const char* Bin[3] = {(const char*)wthi, (const char*)wthi, (const char*)wtlo};
    const size_t abase = (size_t)b * 128 * 512;          // row j stride 512B (256 k * 2B)
    const size_t bbase = (size_t)dh * 128 * 512;         // row n stride 512B

    f32x4 z = {0.f, 0.f, 0.f, 0.f};
    f32x4 acc[4][4];
    #pragma unroll
    for (int mi = 0; mi < 4; ++mi)
        #pragma unroll
        for (int ni = 0; ni < 4; ++ni) acc[mi][ni] = z;

    for (int q = 0; q < 12; ++q) {
        const char* Aseg = Ain[q >> 2] + abase + (q & 3) * 128;
        const char* Bseg = Bin[q >> 2] + bbase + (q & 3) * 128;
        #pragma unroll
        for (int u = 0; u < 4; ++u) {
            int off = (u * 256 + tid) * 16;
            int row = off >> 7, col = off & 127;
            *(uint4*)(As + off) = *(const uint4*)(Aseg + (size_t)row * 512 + col);
        }
        #pragma unroll
        for (int u = 0; u < 4; ++u) {
            int off = (u * 256 + tid) * 16;
            int row = off >> 7, col = off & 127;
            *(uint4*)(Bs + off) = *(const uint4*)(Bseg + (size_t)row * 512 + col);
        }
        __syncthreads();
        #pragma unroll
        for (int kk = 0; kk < 2; ++kk) {
            short8 a[4], bf8[4];
            #pragma unroll
            for (int mi = 0; mi < 4; ++mi)
                a[mi] = *(const short8*)(As + (wr * 64 + mi * 16 + lr) * 128 + kk * 64 + lkb);
            #pragma unroll
            for (int ni = 0; ni < 4; ++ni)
                bf8[ni] = *(const short8*)(Bs + (wc * 64 + ni * 16 + lr) * 128 + kk * 64 + lkb);
            #pragma unroll
            for (int mi = 0; mi < 4; ++mi)
                #pragma unroll
                for (int ni = 0; ni < 4; ++ni)
                    acc[mi][ni] = __builtin_amdgcn_mfma_f32_16x16x32_bf16(a[mi], bf8[ni],
                                                                         acc[mi][ni], 0, 0, 0);
        }
        __syncthreads();
    }

    // ---- epilogue 1: +bias, split, store vp to LDS as [d_local][j] (row 256B) ----
    #pragma unroll
    for (int ni = 0; ni < 4; ++ni) {
        int dl = wc * 64 + ni * 16 + lr;
        float bv = bias[dh * 128 + dl];
        #pragma unroll
        for (int mi = 0; mi < 4; ++mi) {
            int j0 = wr * 64 + mi * 16 + (l >> 4) * 4;
            ushort4 hv, lv;
            float v0 = acc[mi][ni][0] + bv;
            float v1 = acc[mi][ni][1] + bv;
            float v2 = acc[mi][ni][2] + bv;
            float v3 = acc[mi][ni][3] + bv;
            hv.x = f2bf(v0); lv.x = f2bf(v0 - bf2f(hv.x));
            hv.y = f2bf(v1); lv.y = f2bf(v1 - bf2f(hv.y));
            hv.z = f2bf(v2); lv.z = f2bf(v2 - bf2f(hv.z));
            hv.w = f2bf(v3); lv.w = f2bf(v3 - bf2f(hv.w));
            *(ushort4*)(VPH + dl * 256 + j0 * 2) = hv;
            *(ushort4*)(VPL + dl * 256 + j0 * 2) = lv;
        }
    }
    __syncthreads();

    // ---- GEMM2: C2[d][i] = sum_j vp[d][j] * Gp[i][j]  (Gp symmetric; K = 2x128 j) ----
    #pragma unroll
    for (int mi = 0; mi < 4; ++mi)
        #pragma unroll
        for (int ni = 0; ni < 4; ++ni) acc[mi][ni] = z;

    #pragma unroll
    for (int s = 0; s < 2; ++s) {
        const char* Aseg = s ? VPL : VPH;
        #pragma unroll
        for (int j0b = 0; j0b < 256; j0b += 128) {
            #pragma unroll
            for (int kk = 0; kk < 2; ++kk) {
                short8 a[4], bf8[4];
                #pragma unroll
                for (int mi = 0; mi < 4; ++mi)
                    a[mi] = *(const short8*)(Aseg + (wr * 64 + mi * 16 + lr) * 256 + j0b + kk * 64 + lkb);
                #pragma unroll
                for (int ni = 0; ni < 4; ++ni)
                    bf8[ni] = *(const short8*)(Gs + (wc * 64 + ni * 16 + lr) * 256 + j0b + kk * 64 + lkb);
                #pragma unroll
                for (int mi = 0; mi < 4; ++mi)
                    #pragma unroll
                    for (int ni = 0; ni < 4; ++ni)
                        acc[mi][ni] = __builtin_amdgcn_mfma_f32_16x16x32_bf16(a[mi], bf8[ni],
                                                                             acc[mi][ni], 0, 0, 0);
            }
        }
    }

    // ---- epilogue 2: v[b][i][d] += relu(C2/deg); write fp32 master + split ----
    #pragma unroll
    for (int ni = 0; ni < 4; ++ni) {
        int i = wc * 64 + ni * 16 + lr;
        int m = b * 128 + i;
        float idg = invdeg[m];
        #pragma unroll
        for (int mi = 0; mi < 4; ++mi) {
            int d = dh * 128 + wr * 64 + mi * 16 + (l >> 4) * 4;
            float* pv = v + (size_t)m * 256 + d;
            float4 c4 = *(float4*)pv;
            float n0v = c4.x + fmaxf(acc[mi][ni][0] * idg, 0.0f);
            float n1v = c4.y + fmaxf(acc[mi][ni][1] * idg, 0.0f);
            float n2v = c4.z + fmaxf(acc[mi][ni][2] * idg, 0.0f);
            float n3v = c4.w + fmaxf(acc[mi][ni][3] * idg, 0.0f);
            *(float4*)pv = make_float4(n0v, n1v, n2v, n3v);
            ushort4 hv, lv;
            hv.x = f2bf(n0v); lv.x = f2bf(n0v - bf2f(hv.x));
            hv.y = f2bf(n1v); lv.y = f2bf(n1v - bf2f(hv.y));
            hv.z = f2bf(n2v); lv.z = f2bf(n2v - bf2f(hv.z));
            hv.w = f2bf(n3v); lv.w = f2bf(n3v - bf2f(hv.w));
            *(ushort4*)(vhi_out + (size_t)m * 256 + d) = hv;
            *(ushort4*)(vlo_out + (size_t)m * 256 + d) = lv;
        }
    }
}

// ---------------- LayerNorm: read v fp32, write split h ----------------
__global__ __launch_bounds__(256) void ln_kernel(const float* __restrict__ v,
                                                 const float* __restrict__ g,
                                                 const float* __restrict__ beta,
                                                 u16* __restrict__ hhi,
                                                 u16* __restrict__ hlo) {
    __shared__ float sbuf[4];
    int row = blockIdx.x;
    int t = threadIdx.x;
    float x = v[(size_t)row * Hdim + t];
    float s = x;
    #pragma unroll
    for (int off = 32; off; off >>= 1) s += __shfl_down(s, off);
    int wid = t >> 6, lane = t & 63;
    if (lane == 0) sbuf[wid] = s;
    __syncthreads();
    float mu = (sbuf[0] + sbuf[1] + sbuf[2] + sbuf[3]) * (1.0f / Hdim);
    __syncthreads();
    float d = x - mu;
    float sq = d * d;
    #pragma unroll
    for (int off = 32; off; off >>= 1) sq += __shfl_down(sq, off);
    if (lane == 0) sbuf[wid] = sq;
    __syncthreads();
    float var = (sbuf[0] + sbuf[1] + sbuf[2] + sbuf[3]) * (1.0f / Hdim);
    float h = d * (1.0f / sqrtf(var + LN_EPS)) * g[t] + beta[t];
    size_t idx = (size_t)row * Hdim + t;
    u16 hb = f2bf(h);
    hhi[idx] = hb;
    hlo[idx] = f2bf(h - bf2f(hb));
}

// ---------------- fused final GEMM (MFMA split): part[m][nb] = sum_n relu(h@Wf+bf)*Wo ----------------
__global__ __launch_bounds__(256) void gemm_fin_mfma(const u16* __restrict__ hhi,
                                                     const u16* __restrict__ hlo,
                                                     const u16* __restrict__ wfhi,
                                                     const u16* __restrict__ wflo,
                                                     const float* __restrict__ bfin,
                                                     const float* __restrict__ wout,
                                                     float* __restrict__ part) {
    __shared__ char smem[24576];
    char* As = smem;
    char* Bs = smem + 16384;
    int tid = threadIdx.x, l = tid & 63, w = tid >> 6, wr = w >> 1, wc = w & 1;
    int m0 = blockIdx.x * 128, n0 = blockIdx.y * 64;
    const char* segA[3] = {(const char*)hhi, (const char*)hlo, (const char*)hhi};
    const char* segB[3] = {(const char*)wfhi, (const char*)wfhi, (const char*)wflo};
    f32x4 z = {0.f, 0.f, 0.f, 0.f};
    f32x4 acc[4][2];
    #pragma unroll
    for (int mi = 0; mi < 4; ++mi) { acc[mi][0] = z; acc[mi][1] = z; }

    for (int q = 0; q < 12; ++q) {
        const char* A = segA[q >> 2] + (size_t)m0 * 512 + (q & 3) * 128;
        const char* B = segB[q >> 2] + (size_t)n0 * 512 + (q & 3) * 128;
        #pragma unroll
        for (int u = 0; u < 4; ++u) {
            int off = (u * 256 + tid) * 16;
            int row = off >> 7, col = off & 127;
            *(uint4*)(As + off) = *(const uint4*)(A + (size_t)row * 512 + col);
        }
        #pragma unroll
        for (int u = 0; u < 2; ++u) {
            int off = (u * 256 + tid) * 16;
            int row = off >> 7, col = off & 127;
            *(uint4*)(Bs + off) = *(const uint4*)(B + (size_t)row * 512 + col);
        }
        __syncthreads();
        const int lr = l & 15;
        const int lkb = (l >> 4) * 16;
        #pragma unroll
        for (int kk = 0; kk < 2; ++kk) {
            short8 a[4], b2[2];
            #pragma unroll
            for (int mi = 0; mi < 4; ++mi)
                a[mi] = *(const short8*)(As + (wr * 64 + mi * 16 + lr) * 128 + kk * 64 + lkb);
            #pragma unroll
            for (int ni = 0; ni < 2; ++ni)
                b2[ni] = *(const short8*)(Bs + (wc * 32 + ni * 16 + lr) * 128 + kk * 64 + lkb);
            #pragma unroll
            for (int mi = 0; mi < 4; ++mi)
                #pragma unroll
                for (int ni = 0; ni < 2; ++ni)
                    acc[mi][ni] = __builtin_amdgcn_mfma_f32_16x16x32_bf16(a[mi], b2[ni],
                                                                         acc[mi][ni], 0, 0, 0);
        }
        __syncthreads();
    }
    float rs[4][4];
    #pragma unroll
    for (int mi = 0; mi < 4; ++mi)
        #pragma unroll
        for (int r = 0; r < 4; ++r) rs[mi][r] = 0.0f;
    #pragma unroll
    for (int ni = 0; ni < 2; ++ni) {
        int n = n0 + wc * 32 + ni * 16 + (l & 15);
        float bv = bfin[n], wo = wout[n];
        #pragma unroll
        for (int mi = 0; mi < 4; ++mi)
            #pragma unroll
            for (int r = 0; r < 4; ++r)
                rs[mi][r] += fmaxf(acc[mi][ni][r] + bv, 0.0f) * wo;
    }
    float* red = (float*)smem;          // [128][33] floats; loop ended with barrier
    #pragma unroll
    for (int mi = 0; mi < 4; ++mi)
        #pragma unroll
        for (int r = 0; r < 4; ++r) {
            int row = wr * 64 + mi * 16 + (l >> 4) * 4 + r;
            red[row * 33 + wc * 16 + (l & 15)] = rs[mi][r];
        }
    __syncthreads();
    if (tid < 128) {
        float s = 0.0f;
        #pragma unroll
        for (int c = 0; c < 32; ++c) s += red[tid * 33 + c];
        part[(size_t)(m0 + tid) * 16 + blockIdx.y] = s;
    }
}

// ---------------- final reduce ----------------
__global__ __launch_bounds__(256) void final_kernel(const float* __restrict__ part,
                                                    const float* __restrict__ bo,
                                                    float* __restrict__ out) {
    int i = blockIdx.x * 256 + threadIdx.x;
    float s = bo[0];
    #pragma unroll
    for (int t = 0; t < 16; ++t) s += part[(size_t)i * 16 + t];
    out[i] = s;
}

extern "C" void kernel_launch(void* const* d_in, const int* in_sizes, int n_in,
                              void* d_out, int out_size, void* d_ws, size_t ws_size,
                              hipStream_t stream) {
    const float* x        = (const float*)d_in[0];
    const float* G        = (const float*)d_in[1];
    const float* W_feat   = (const float*)d_in[2];
    const float* b_feat   = (const float*)d_in[3];
    const float* W_layers = (const float*)d_in[4];
    const float* b_layers = (const float*)d_in[5];
    const float* ln_g     = (const float*)d_in[6];
    const float* ln_b     = (const float*)d_in[7];
    const float* W_fin    = (const float*)d_in[8];
    const float* b_fin    = (const float*)d_in[9];
    const float* W_out    = (const float*)d_in[10];
    const float* b_out    = (const float*)d_in[11];
    float* out = (float*)d_out;

    const int M = Bsz * Vn;                          // 16384
    char* ws = (char*)d_ws;
    float* v      = (float*)ws;                      ws += (size_t)M * Hdim * 4;     // 16 MB
    u16*   vh0    = (u16*)ws;                        ws += (size_t)M * Hdim * 2;     // 8 MB
    u16*   vl0    = (u16*)ws;                        ws += (size_t)M * Hdim * 2;     // 8 MB
    u16*   vh1    = (u16*)ws;                        ws += (size_t)M * Hdim * 2;     // 8 MB
    u16*   vl1    = (u16*)ws;                        ws += (size_t)M * Hdim * 2;     // 8 MB
    u16*   gbf    = (u16*)ws;                        ws += (size_t)Bsz * Vn * Vn * 2;   // 4 MB
    u16*   wthi   = (u16*)ws;                        ws += (size_t)Lnum * Hdim * Hdim * 2; // 4 MB
    u16*   wtlo   = (u16*)ws;                        ws += (size_t)Lnum * Hdim * Hdim * 2; // 4 MB
    u16*   wfhi   = (u16*)ws;                        ws += (size_t)FLdim * Hdim * 2;  // 0.5 MB
    u16*   wflo   = (u16*)ws;                        ws += (size_t)FLdim * Hdim * 2;  // 0.5 MB
    float* nrow   = (float*)ws;                      ws += (size_t)M * 4;
    float* invdeg = (float*)ws;                      ws += (size_t)M * 4;
    float* part   = (float*)ws;                      ws += (size_t)M * 16 * 4;        // 1 MB

    u16* vh[2] = {vh0, vh1};
    u16* vl[2] = {vl0, vl1};

    hipFuncSetAttribute((const void*)layer_fused,
                        hipFuncAttributeMaxDynamicSharedMemorySize, 131072);

    rowsum_kernel<<<M / 4, 256, 0, stream>>>(G, nrow, invdeg);
    gbf_kernel<<<(Bsz * Vn * 16) / 256, 256, 0, stream>>>(G, nrow, gbf);
    tsplit_kernel<<<dim3(4, 4, Lnum), 256, 0, stream>>>(W_layers, wthi, wtlo, Hdim, Hdim);
    tsplit_kernel<<<dim3(4, 16, 1), 256, 0, stream>>>(W_fin, wfhi, wflo, FLdim, Hdim);
    feat_kernel<<<M, 256, 0, stream>>>(x, W_feat, b_feat, v, vh0, vl0);

    for (int l = 0; l < Lnum; ++l) {
        int in = l & 1, o = in ^ 1;
        layer_fused<<<dim3(2, Bsz), 256, 131072, stream>>>(
            vh[in], vl[in],
            wthi + (size_t)l * Hdim * Hdim, wtlo + (size_t)l * Hdim * Hdim,
            b_layers + (size_t)l * Hdim,
            gbf, invdeg, v, vh[o], vl[o]);
    }

    ln_kernel<<<M, 256, 0, stream>>>(v, ln_g, ln_b, vh0, vl0);
    gemm_fin_mfma<<<dim3(M / 128, FLdim / 64), 256, 0, stream>>>(
        vh0, vl0, wfhi, wflo, b_fin, W_out, part);
    final_kernel<<<M / 256, 256, 0, stream>>>(part, b_out, out);
}